// Round 1
// baseline (1156.303 us; speedup 1.0000x reference)
//
#include <hip/hip_runtime.h>
#include <math.h>

#define NROWS 8192
#define DIM   512
#define NCLS  10
#define NT    8          // DIM/64 tile chunks
#define NPAIR 36         // lower-triangle 64x64 tile pairs
#define NMAT  32
#define TCOLS 448        // max trailing columns in a panel

// ---------------------------------------------------------------- counts/lists
__global__ __launch_bounds__(256) void k_count(const int* __restrict__ label,
                                               int* __restrict__ counts,
                                               int* __restrict__ lists) {
    int i = blockIdx.x * 256 + threadIdx.x;
    if (i < NROWS) {
        int c = label[i];
        int pos = atomicAdd(&counts[c], 1);
        lists[(size_t)c * NROWS + pos] = i;
    }
}

// ---------------------------------------------------------------- per-class Grams
// G packed: [tensor(2)][class(10)][pair(36)][64*64], lower-triangle tile pairs ti>=tj
__global__ __launch_bounds__(256) void k_gram(const float* __restrict__ Z,
                                              const float* __restrict__ Zb,
                                              const int* __restrict__ counts,
                                              const int* __restrict__ lists,
                                              float* __restrict__ G) {
    int pair = blockIdx.x;
    int c    = blockIdx.y;
    int tz   = blockIdx.z;
    int ti = 0, tj = 0;
    { int p = pair;
      for (int r = 0; r < NT; ++r) { if (p <= r) { ti = r; tj = p; break; } p -= (r + 1); } }

    const float* __restrict__ src = tz ? Zb : Z;
    float* __restrict__ Gout = G + (((size_t)tz * NCLS + c) * NPAIR + pair) * 4096;
    int cnt = counts[c];
    const int* __restrict__ list = lists + (size_t)c * NROWS;

    __shared__ float As[8][64];
    __shared__ float Bs[8][64];
    int tid = threadIdx.x;
    int tx = tid & 15, ty = tid >> 4;

    float acc[4][4];
    #pragma unroll
    for (int r = 0; r < 4; ++r)
        #pragma unroll
        for (int s = 0; s < 4; ++s) acc[r][s] = 0.f;

    bool diag = (ti == tj);

    for (int base = 0; base < cnt; base += 8) {
        for (int idx = tid; idx < 512; idx += 256) {
            int rr = idx >> 6, cc = idx & 63;
            int gr = base + rr;
            float va = 0.f, vb = 0.f;
            if (gr < cnt) {
                int ridx = list[gr];
                va = src[(size_t)ridx * DIM + ti * 64 + cc];
                if (!diag) vb = src[(size_t)ridx * DIM + tj * 64 + cc];
            }
            As[rr][cc] = va;
            if (!diag) Bs[rr][cc] = vb;
        }
        __syncthreads();
        #pragma unroll
        for (int rr = 0; rr < 8; ++rr) {
            float av[4], bv[4];
            *(float4*)av = *(const float4*)&As[rr][ty * 4];
            if (diag) *(float4*)bv = *(const float4*)&As[rr][tx * 4];
            else      *(float4*)bv = *(const float4*)&Bs[rr][tx * 4];
            #pragma unroll
            for (int r = 0; r < 4; ++r)
                #pragma unroll
                for (int s = 0; s < 4; ++s)
                    acc[r][s] += av[r] * bv[s];
        }
        __syncthreads();
    }
    #pragma unroll
    for (int r = 0; r < 4; ++r) {
        float4 v = make_float4(acc[r][0], acc[r][1], acc[r][2], acc[r][3]);
        *(float4*)&Gout[(size_t)(ty * 4 + r) * 64 + tx * 4] = v;
    }
}

// ---------------------------------------------------------------- assemble 32 SPD matrices
// m 0..9: I + sz_c*Gz[c]; 10..19: I + szb_c*Gzb[c]; 20..29: I + s3_c*(Gz+Gzb);
// 30: I + 0.125*sum_c Gz[c]; 31: I + 0.125*sum_c Gzb[c].  Full symmetric store.
__global__ __launch_bounds__(256) void k_assemble(const float* __restrict__ G,
                                                  const int* __restrict__ counts,
                                                  float* __restrict__ A) {
    int pair = blockIdx.x;
    int m    = blockIdx.y;
    int ti = 0, tj = 0;
    { int p = pair;
      for (int r = 0; r < NT; ++r) { if (p <= r) { ti = r; tj = p; break; } p -= (r + 1); } }

    const size_t TILE = 4096;
    const float* __restrict__ Gz  = G;
    const float* __restrict__ Gzb = G + (size_t)NCLS * NPAIR * TILE;
    float* __restrict__ Am = A + (size_t)m * DIM * DIM;
    int tid = threadIdx.x, tx = tid & 15, ty = tid >> 4;
    __shared__ float Vl[64][65];

    int mode; int c; float sc;
    if (m < 10)      { mode = 0; c = m;      sc = 1024.f / ((float)counts[c] + 1e-8f); }
    else if (m < 20) { mode = 1; c = m - 10; sc = 1024.f / ((float)counts[c] + 1e-8f); }
    else if (m < 30) { mode = 2; c = m - 20; sc = 512.f / (float)counts[c]; }
    else             { mode = (m == 30) ? 3 : 4; c = 0; sc = 0.125f; }

    float v[4][4];
    #pragma unroll
    for (int r = 0; r < 4; ++r) {
        int il = ty * 4 + r;
        size_t off = (size_t)il * 64 + tx * 4;
        float4 g = make_float4(0.f, 0.f, 0.f, 0.f);
        if (mode == 0) {
            g = *(const float4*)&Gz[((size_t)c * NPAIR + pair) * TILE + off];
        } else if (mode == 1) {
            g = *(const float4*)&Gzb[((size_t)c * NPAIR + pair) * TILE + off];
        } else if (mode == 2) {
            float4 a = *(const float4*)&Gz [((size_t)c * NPAIR + pair) * TILE + off];
            float4 b = *(const float4*)&Gzb[((size_t)c * NPAIR + pair) * TILE + off];
            g.x = a.x + b.x; g.y = a.y + b.y; g.z = a.z + b.z; g.w = a.w + b.w;
        } else if (mode == 3) {
            for (int cc = 0; cc < NCLS; ++cc) {
                float4 t = *(const float4*)&Gz[((size_t)cc * NPAIR + pair) * TILE + off];
                g.x += t.x; g.y += t.y; g.z += t.z; g.w += t.w;
            }
        } else {
            for (int cc = 0; cc < NCLS; ++cc) {
                float4 t = *(const float4*)&Gzb[((size_t)cc * NPAIR + pair) * TILE + off];
                g.x += t.x; g.y += t.y; g.z += t.z; g.w += t.w;
            }
        }
        v[r][0] = sc * g.x; v[r][1] = sc * g.y; v[r][2] = sc * g.z; v[r][3] = sc * g.w;
    }
    if (ti == tj) {
        #pragma unroll
        for (int r = 0; r < 4; ++r) {
            int il = ty * 4 + r;
            #pragma unroll
            for (int s = 0; s < 4; ++s)
                if (il == tx * 4 + s) v[r][s] += 1.f;
        }
    }
    #pragma unroll
    for (int r = 0; r < 4; ++r) {
        float4 w = make_float4(v[r][0], v[r][1], v[r][2], v[r][3]);
        *(float4*)&Am[(size_t)(ti * 64 + ty * 4 + r) * DIM + tj * 64 + tx * 4] = w;
    }
    if (ti != tj) {
        #pragma unroll
        for (int r = 0; r < 4; ++r)
            #pragma unroll
            for (int s = 0; s < 4; ++s)
                Vl[ty * 4 + r][tx * 4 + s] = v[r][s];
        __syncthreads();
        #pragma unroll
        for (int r = 0; r < 4; ++r) {
            int row = ty * 4 + r;   // = jl of original tile
            float4 w;
            w.x = Vl[tx * 4 + 0][row];
            w.y = Vl[tx * 4 + 1][row];
            w.z = Vl[tx * 4 + 2][row];
            w.w = Vl[tx * 4 + 3][row];
            *(float4*)&Am[(size_t)(tj * 64 + row) * DIM + ti * 64 + tx * 4] = w;
        }
    }
}

// ---------------------------------------------------------------- blocked Cholesky logdet
// One block per matrix. Upper-triangle, row-major. logdet = 2*sum log(U_kk).
__global__ __launch_bounds__(512) void k_chol(float* __restrict__ A,
                                              float* __restrict__ Tbuf,
                                              float* __restrict__ ld) {
    int m = blockIdx.x;
    float* __restrict__ Am = A + (size_t)m * DIM * DIM;
    float* __restrict__ Tm = Tbuf + (size_t)m * 64 * TCOLS;
    int tid = threadIdx.x;

    __shared__ float Dl[64][65];
    __shared__ float TlA[64][64];
    __shared__ float TlB[64][64];

    #pragma unroll 1
    for (int p = 0; p < NT; ++p) {
        int col0 = p * 64;
        int col1 = col0 + 64;
        int mt = DIM - col1;

        // load diagonal tile
        for (int q = tid; q < 64 * 16; q += 512) {
            int i = q >> 4, cc = (q & 15) * 4;
            *(float4*)&Dl[i][cc] = *(const float4*)&Am[(size_t)(col0 + i) * DIM + col0 + cc];
        }
        __syncthreads();

        // factorize 64x64 diag block (upper Cholesky), right-looking
        for (int k = 0; k < 64; ++k) {
            if (tid < 64) {   // exactly wave 0: read-before-write safe in lockstep
                float piv = Dl[k][k];
                float sq = sqrtf(piv);
                if (tid > k)       Dl[k][tid] /= sq;
                else if (tid == k) Dl[k][k] = sq;
            }
            __syncthreads();
            int j = tid & 63;
            for (int i = k + 1 + (tid >> 6); i < 64; i += 8) {
                if (j >= i) Dl[i][j] -= Dl[k][i] * Dl[k][j];
            }
            __syncthreads();
        }

        // logdet contribution of this panel
        if (tid < 64) {
            float v = 2.f * logf(Dl[tid][tid]);
            #pragma unroll
            for (int off = 32; off > 0; off >>= 1) v += __shfl_down(v, off);
            if (tid == 0) atomicAdd(&ld[m], v);
        }

        // trsm: T = U_d^{-T} * B, column-parallel, T -> global
        if (mt > 0 && tid < mt) {
            float t[64];
            const float* __restrict__ Brow = Am + (size_t)col0 * DIM + col1 + tid;
            #pragma unroll
            for (int i = 0; i < 64; ++i) {
                float acc = Brow[(size_t)i * DIM];
                #pragma unroll
                for (int mm = 0; mm < i; ++mm) acc -= Dl[mm][i] * t[mm];
                t[i] = acc / Dl[i][i];
            }
            #pragma unroll
            for (int i = 0; i < 64; ++i) Tm[i * TCOLS + tid] = t[i];
        }
        __syncthreads();

        // trailing update: C -= T^T T, 64x64 tiles, upper pairs only
        int K = NT - 1 - p;
        for (int a = 0; a < K; ++a) {
            for (int b = a; b < K; ++b) {
                for (int q = tid; q < 64 * 16; q += 512) {
                    int i = q >> 4, cc = (q & 15) * 4;
                    *(float4*)&TlA[i][cc] = *(const float4*)&Tm[i * TCOLS + a * 64 + cc];
                }
                if (b != a) {
                    for (int q = tid; q < 64 * 16; q += 512) {
                        int i = q >> 4, cc = (q & 15) * 4;
                        *(float4*)&TlB[i][cc] = *(const float4*)&Tm[i * TCOLS + b * 64 + cc];
                    }
                }
                __syncthreads();
                int jl0 = (tid & 15) * 4;
                int il0 = (tid >> 4) * 2;
                float4 acc0 = make_float4(0.f, 0.f, 0.f, 0.f);
                float4 acc1 = make_float4(0.f, 0.f, 0.f, 0.f);
                const float (*__restrict__ TB)[64] = (b != a) ? TlB : TlA;
                #pragma unroll 8
                for (int mm = 0; mm < 64; ++mm) {
                    float a0 = TlA[mm][il0];
                    float a1 = TlA[mm][il0 + 1];
                    float4 bb = *(const float4*)&TB[mm][jl0];
                    acc0.x += a0 * bb.x; acc0.y += a0 * bb.y;
                    acc0.z += a0 * bb.z; acc0.w += a0 * bb.w;
                    acc1.x += a1 * bb.x; acc1.y += a1 * bb.y;
                    acc1.z += a1 * bb.z; acc1.w += a1 * bb.w;
                }
                size_t I0 = (size_t)col1 + a * 64 + il0;
                size_t J0 = (size_t)col1 + b * 64 + jl0;
                float4* c0 = (float4*)&Am[I0 * DIM + J0];
                float4* c1 = (float4*)&Am[(I0 + 1) * DIM + J0];
                float4 v0 = *c0, v1 = *c1;
                v0.x -= acc0.x; v0.y -= acc0.y; v0.z -= acc0.z; v0.w -= acc0.w;
                v1.x -= acc1.x; v1.y -= acc1.y; v1.z -= acc1.z; v1.w -= acc1.w;
                *c0 = v0; *c1 = v1;
                __syncthreads();
            }
        }
    }
}

// ---------------------------------------------------------------- finalize
__global__ void k_final(const float* __restrict__ ld,
                        const int* __restrict__ counts,
                        float* __restrict__ out) {
    if (threadIdx.x == 0 && blockIdx.x == 0) {
        float disc_z  = 0.5f * ld[30];
        float disc_zb = 0.5f * ld[31];
        float comp_z = 0.f, comp_zb = 0.f, sum_ldz = 0.f, sum_ldzb = 0.f, item = 0.f;
        for (int c = 0; c < NCLS; ++c) {
            float cnt = (float)counts[c];
            float trPi = cnt + 1e-8f;
            float s = trPi / (2.f * (float)NROWS);
            comp_z  += s * ld[c];
            comp_zb += s * ld[10 + c];
            sum_ldz  += ld[c];
            sum_ldzb += ld[10 + c];
            item += 0.5f * ld[20 + c];
        }
        float term3 = item - 0.25f * sum_ldz - 0.25f * sum_ldzb;
        float z_total  = -(disc_z - comp_z);
        float zb_total = -(disc_zb - comp_zb);
        float errD = -((disc_z - comp_z) + (disc_zb - comp_zb) + term3);
        out[0] = errD; out[1] = z_total; out[2] = zb_total; out[3] = term3;
    }
}

// ---------------------------------------------------------------- launch
extern "C" void kernel_launch(void* const* d_in, const int* in_sizes, int n_in,
                              void* d_out, int out_size, void* d_ws, size_t ws_size,
                              hipStream_t stream) {
    (void)in_sizes; (void)n_in; (void)out_size; (void)ws_size;
    const float* Z     = (const float*)d_in[0];
    const float* Zb    = (const float*)d_in[1];
    const int*   label = (const int*)d_in[2];
    // d_in[3] = num_classes, fixed at 10 by the harness setup.

    char* ws = (char*)d_ws;
    int*   counts = (int*)ws;                                   // 64 B
    float* ld     = (float*)(ws + 64);                          // 128 B
    int*   lists  = (int*)(ws + 256);                           // 10*8192*4
    float* G      = (float*)(ws + 256 + (size_t)NCLS * NROWS * 4);
    float* A      = G + (size_t)2 * NCLS * NPAIR * 4096;        // 32 MiB
    float* Tb     = A + (size_t)NMAT * DIM * DIM;               // 32 * 64*448
    float* out    = (float*)d_out;

    hipMemsetAsync(ws, 0, 256, stream);
    k_count<<<NROWS / 256, 256, 0, stream>>>(label, counts, lists);
    k_gram<<<dim3(NPAIR, NCLS, 2), 256, 0, stream>>>(Z, Zb, counts, lists, G);
    k_assemble<<<dim3(NPAIR, NMAT), 256, 0, stream>>>(G, counts, A);
    k_chol<<<NMAT, 512, 0, stream>>>(A, Tb, ld);
    k_final<<<1, 64, 0, stream>>>(ld, counts, out);
}

// Round 3
// 788.742 us; speedup vs baseline: 1.4660x; 1.4660x over previous
//
#include <hip/hip_runtime.h>
#include <math.h>

#define NROWS 8192
#define DIM   512
#define NCLS  10
#define GT    4        // 128-wide tile grid (4x4)
#define GPAIR 10       // lower-triangle 128-tile pairs
#define NMAT  32
#define TSTRIDE 448    // Tt row stride (max trailing cols)

// ---------------------------------------------------------------- counts/lists
__global__ __launch_bounds__(256) void k_count(const int* __restrict__ label,
                                               int* __restrict__ counts,
                                               int* __restrict__ lists) {
    int i = blockIdx.x * 256 + threadIdx.x;
    if (i < NROWS) {
        int c = label[i];
        int pos = atomicAdd(&counts[c], 1);
        lists[(size_t)c * NROWS + pos] = i;
    }
}

// ---------------------------------------------------------------- per-class Grams
// G packed: [tensor(2)][class(10)][pair(10)][128*128]; lower pairs ti>=tj over 4x4.
__global__ __launch_bounds__(256) void k_gram(const float* __restrict__ Z,
                                              const float* __restrict__ Zb,
                                              const int* __restrict__ counts,
                                              const int* __restrict__ lists,
                                              float* __restrict__ G) {
    int pt = blockIdx.x;
    int c  = blockIdx.y;
    int tz = blockIdx.z;
    int ti = 0, tj = 0;
    { int p = pt;
      for (int r = 0; r < GT; ++r) { if (p <= r) { ti = r; tj = p; break; } p -= (r + 1); } }
    bool diag = (ti == tj);

    const float* __restrict__ src = tz ? Zb : Z;
    float* __restrict__ Gout = G + (((size_t)tz * NCLS + c) * GPAIR + pt) * 16384;
    int cnt = counts[c];
    const int* __restrict__ list = lists + (size_t)c * NROWS;

    __shared__ float As[8][128];
    __shared__ float Bs[8][128];
    int tid = threadIdx.x;
    int tx = tid & 15, ty = tid >> 4;   // 16x16 thread grid, 8x8 per thread

    float acc[8][8];
    #pragma unroll
    for (int r = 0; r < 8; ++r)
        #pragma unroll
        for (int s = 0; s < 8; ++s) acc[r][s] = 0.f;

    int lr = tid >> 5, lc4 = tid & 31;   // staging: row 0..7, f4-col 0..31

    for (int base = 0; base < cnt; base += 8) {
        int gr = base + lr;
        float4 va = make_float4(0.f, 0.f, 0.f, 0.f);
        float4 vb = va;
        if (gr < cnt) {
            int ridx = list[gr];
            va = *(const float4*)&src[(size_t)ridx * DIM + ti * 128 + lc4 * 4];
            if (!diag) vb = *(const float4*)&src[(size_t)ridx * DIM + tj * 128 + lc4 * 4];
        }
        *(float4*)&As[lr][lc4 * 4] = va;
        if (!diag) *(float4*)&Bs[lr][lc4 * 4] = vb;
        __syncthreads();

        const float (*__restrict__ Bp)[128] = diag ? As : Bs;
        #pragma unroll
        for (int kk = 0; kk < 8; ++kk) {
            float a[8], b[8];
            *(float4*)&a[0] = *(const float4*)&As[kk][ty * 8];
            *(float4*)&a[4] = *(const float4*)&As[kk][ty * 8 + 4];
            *(float4*)&b[0] = *(const float4*)&Bp[kk][tx * 8];
            *(float4*)&b[4] = *(const float4*)&Bp[kk][tx * 8 + 4];
            #pragma unroll
            for (int r = 0; r < 8; ++r)
                #pragma unroll
                for (int s = 0; s < 8; ++s)
                    acc[r][s] += a[r] * b[s];
        }
        __syncthreads();
    }
    #pragma unroll
    for (int r = 0; r < 8; ++r) {
        float4 v0 = make_float4(acc[r][0], acc[r][1], acc[r][2], acc[r][3]);
        float4 v1 = make_float4(acc[r][4], acc[r][5], acc[r][6], acc[r][7]);
        size_t row = (size_t)(ty * 8 + r) * 128 + tx * 8;
        *(float4*)&Gout[row]     = v0;
        *(float4*)&Gout[row + 4] = v1;
    }
}

// ---------------------------------------------------------------- assemble (lower tiles only)
// m 0..9: I + (1024/(cnt+1e-8))*Gz[c]; 10..19: same Gzb; 20..29: I + (512/cnt)*(Gz+Gzb);
// 30: I + 0.125*sum Gz; 31: I + 0.125*sum Gzb
__global__ __launch_bounds__(256) void k_assemble(const float* __restrict__ G,
                                                  const int* __restrict__ counts,
                                                  float* __restrict__ A) {
    int pt = blockIdx.x;
    int m  = blockIdx.y;
    int ti = 0, tj = 0;
    { int p = pt;
      for (int r = 0; r < GT; ++r) { if (p <= r) { ti = r; tj = p; break; } p -= (r + 1); } }

    const size_t TILE = 16384;
    const float* __restrict__ Gz  = G;
    const float* __restrict__ Gzb = G + (size_t)NCLS * GPAIR * TILE;
    float* __restrict__ Am = A + (size_t)m * DIM * DIM;
    int tid = threadIdx.x;

    int mode; int c; float sc;
    if (m < 10)      { mode = 0; c = m;      sc = 1024.f / ((float)counts[c] + 1e-8f); }
    else if (m < 20) { mode = 1; c = m - 10; sc = 1024.f / ((float)counts[c] + 1e-8f); }
    else if (m < 30) { mode = 2; c = m - 20; sc = 512.f / (float)counts[c]; }
    else             { mode = (m == 30) ? 3 : 4; c = 0; sc = 0.125f; }

    #pragma unroll 1
    for (int h = 0; h < 16; ++h) {
        int id = h * 256 + tid;
        int row = id >> 5, c4 = id & 31;
        size_t off = (size_t)row * 128 + c4 * 4;
        float4 g = make_float4(0.f, 0.f, 0.f, 0.f);
        if (mode == 0) {
            g = *(const float4*)&Gz[((size_t)c * GPAIR + pt) * TILE + off];
        } else if (mode == 1) {
            g = *(const float4*)&Gzb[((size_t)c * GPAIR + pt) * TILE + off];
        } else if (mode == 2) {
            float4 a = *(const float4*)&Gz [((size_t)c * GPAIR + pt) * TILE + off];
            float4 b = *(const float4*)&Gzb[((size_t)c * GPAIR + pt) * TILE + off];
            g.x = a.x + b.x; g.y = a.y + b.y; g.z = a.z + b.z; g.w = a.w + b.w;
        } else if (mode == 3) {
            for (int cc = 0; cc < NCLS; ++cc) {
                float4 t = *(const float4*)&Gz[((size_t)cc * GPAIR + pt) * TILE + off];
                g.x += t.x; g.y += t.y; g.z += t.z; g.w += t.w;
            }
        } else {
            for (int cc = 0; cc < NCLS; ++cc) {
                float4 t = *(const float4*)&Gzb[((size_t)cc * GPAIR + pt) * TILE + off];
                g.x += t.x; g.y += t.y; g.z += t.z; g.w += t.w;
            }
        }
        g.x *= sc; g.y *= sc; g.z *= sc; g.w *= sc;
        if (ti == tj) {
            int cb = c4 * 4;
            if (row == cb)     g.x += 1.f;
            if (row == cb + 1) g.y += 1.f;
            if (row == cb + 2) g.z += 1.f;
            if (row == cb + 3) g.w += 1.f;
        }
        *(float4*)&Am[(size_t)(ti * 128 + row) * DIM + tj * 128 + c4 * 4] = g;
    }
}

// ---------------------------------------------------------------- panel: fact(64x64) + trsm
// Lower Cholesky A = L L^T. Wave 0 factorizes diag block in registers (row per lane).
// All waves then solve T = P * L_d^{-T} row-per-thread; T stored TRANSPOSED: Tt[k][r].
__global__ __launch_bounds__(512) void k_panel(float* __restrict__ A,
                                               float* __restrict__ Tt,
                                               float* __restrict__ ld,
                                               int p) {
    int m = blockIdx.x;
    float* __restrict__ Am = A + (size_t)m * DIM * DIM;
    float* __restrict__ Tm = Tt + (size_t)m * 64 * TSTRIDE;
    int col0 = p * 64, col1 = col0 + 64;
    int mt = DIM - col1;
    int tid = threadIdx.x;

    __shared__ float Dl[64][65];
    __shared__ float dinv[64];

    for (int h = tid; h < 1024; h += 512) {
        int r = h >> 4, c4 = h & 15;
        *(float4*)&Dl[r][c4 * 4] = *(const float4*)&Am[(size_t)(col0 + r) * DIM + col0 + c4 * 4];
    }
    __syncthreads();

    if (tid < 64) {
        int lane = tid;
        float row_[64];
        #pragma unroll
        for (int j = 0; j < 64; ++j) row_[j] = Dl[lane][j];
        float dval = 1.f;
        #pragma unroll
        for (int k = 0; k < 64; ++k) {
            float piv = __shfl(row_[k], k);
            float s = 1.0f / sqrtf(piv);
            float lik = row_[k] * s;
            dval = (lane == k) ? lik : dval;
            row_[k] = lik;
            #pragma unroll
            for (int j = k + 1; j < 64; ++j)
                row_[j] -= lik * __shfl(lik, j);
        }
        #pragma unroll
        for (int j = 0; j < 64; ++j) Dl[lane][j] = row_[j];
        dinv[lane] = 1.f / dval;
        float v = 2.f * logf(dval);
        #pragma unroll
        for (int off = 32; off > 0; off >>= 1) v += __shfl_down(v, off);
        if (lane == 0) atomicAdd(&ld[m], v);
    }
    __syncthreads();

    if (tid < mt) {
        const float* __restrict__ Brow = Am + (size_t)(col1 + tid) * DIM + col0;
        float t[64];
        #pragma unroll
        for (int i = 0; i < 64; ++i) {
            float acc0 = Brow[i], acc1 = 0.f;
            int mm = 0;
            #pragma unroll
            for (; mm + 1 < i; mm += 2) {
                acc0 -= t[mm]     * Dl[i][mm];
                acc1 -= t[mm + 1] * Dl[i][mm + 1];
            }
            if (mm < i) acc0 -= t[mm] * Dl[i][mm];
            t[i] = (acc0 + acc1) * dinv[i];
            Tm[i * TSTRIDE + tid] = t[i];
        }
    }
}

// ---------------------------------------------------------------- trailing syrk
// C[i][j] -= sum_k Tt[k][a64+i] * Tt[k][b64+j], lower pairs a>=b.
__global__ __launch_bounds__(256) void k_syrk(float* __restrict__ A,
                                              const float* __restrict__ Tt,
                                              int p) {
    int m = blockIdx.y;
    int K = 7 - p;
    int a = 0, b = 0;
    { int q = blockIdx.x;
      for (int r = 0; r < K; ++r) { if (q <= r) { a = r; b = q; break; } q -= (r + 1); } }

    float* __restrict__ Am = A + (size_t)m * DIM * DIM;
    const float* __restrict__ Tm = Tt + (size_t)m * 64 * TSTRIDE;
    int col1 = p * 64 + 64;

    __shared__ float Ta[8][64];
    __shared__ float Tb[8][64];
    int tid = threadIdx.x, tx = tid & 15, ty = tid >> 4;

    float acc[4][4];
    #pragma unroll
    for (int r = 0; r < 4; ++r)
        #pragma unroll
        for (int s = 0; s < 4; ++s) acc[r][s] = 0.f;

    // 128 threads per half; each half stages 8 rows x 16 float4 (= 8x64 floats)
    int half = tid >> 7, w = tid & 127, kk0 = w >> 4, c40 = w & 15;

    for (int k0 = 0; k0 < 64; k0 += 8) {
        float4 v = *(const float4*)&Tm[(k0 + kk0) * TSTRIDE + (half ? b : a) * 64 + c40 * 4];
        if (half) *(float4*)&Tb[kk0][c40 * 4] = v;
        else      *(float4*)&Ta[kk0][c40 * 4] = v;
        __syncthreads();
        #pragma unroll
        for (int kk = 0; kk < 8; ++kk) {
            float av[4], bv[4];
            *(float4*)av = *(const float4*)&Ta[kk][ty * 4];
            *(float4*)bv = *(const float4*)&Tb[kk][tx * 4];
            #pragma unroll
            for (int r = 0; r < 4; ++r)
                #pragma unroll
                for (int s = 0; s < 4; ++s)
                    acc[r][s] += av[r] * bv[s];
        }
        __syncthreads();
    }
    #pragma unroll
    for (int r = 0; r < 4; ++r) {
        size_t off = (size_t)(col1 + a * 64 + ty * 4 + r) * DIM + col1 + b * 64 + tx * 4;
        float4 cv = *(float4*)&Am[off];
        cv.x -= acc[r][0]; cv.y -= acc[r][1]; cv.z -= acc[r][2]; cv.w -= acc[r][3];
        *(float4*)&Am[off] = cv;
    }
}

// ---------------------------------------------------------------- finalize
__global__ void k_final(const float* __restrict__ ld,
                        const int* __restrict__ counts,
                        float* __restrict__ out) {
    if (threadIdx.x == 0 && blockIdx.x == 0) {
        float disc_z  = 0.5f * ld[30];
        float disc_zb = 0.5f * ld[31];
        float comp_z = 0.f, comp_zb = 0.f, sum_ldz = 0.f, sum_ldzb = 0.f, item = 0.f;
        for (int c = 0; c < NCLS; ++c) {
            float trPi = (float)counts[c] + 1e-8f;
            float s = trPi / (2.f * (float)NROWS);
            comp_z  += s * ld[c];
            comp_zb += s * ld[10 + c];
            sum_ldz  += ld[c];
            sum_ldzb += ld[10 + c];
            item += 0.5f * ld[20 + c];
        }
        float term3 = item - 0.25f * sum_ldz - 0.25f * sum_ldzb;
        float z_total  = -(disc_z - comp_z);
        float zb_total = -(disc_zb - comp_zb);
        float errD = -((disc_z - comp_z) + (disc_zb - comp_zb) + term3);
        out[0] = errD; out[1] = z_total; out[2] = zb_total; out[3] = term3;
    }
}

// ---------------------------------------------------------------- launch
extern "C" void kernel_launch(void* const* d_in, const int* in_sizes, int n_in,
                              void* d_out, int out_size, void* d_ws, size_t ws_size,
                              hipStream_t stream) {
    (void)in_sizes; (void)n_in; (void)out_size; (void)ws_size;
    const float* Z     = (const float*)d_in[0];
    const float* Zb    = (const float*)d_in[1];
    const int*   label = (const int*)d_in[2];

    char* ws = (char*)d_ws;
    int*   counts = (int*)ws;                                    // 40 B
    float* ld     = (float*)(ws + 64);                           // 128 B
    int*   lists  = (int*)(ws + 256);                            // 10*8192*4 = 320 KiB
    float* G      = (float*)(ws + 256 + (size_t)NCLS * NROWS * 4);        // 13.1 MiB
    float* Tt     = G;                                           // alias: G dead after assemble
    float* A      = G + (size_t)2 * NCLS * GPAIR * 16384;        // 32 MiB
    float* out    = (float*)d_out;

    hipMemsetAsync(ws, 0, 256, stream);
    k_count<<<NROWS / 256, 256, 0, stream>>>(label, counts, lists);
    k_gram<<<dim3(GPAIR, NCLS, 2), 256, 0, stream>>>(Z, Zb, counts, lists, G);
    k_assemble<<<dim3(GPAIR, NMAT), 256, 0, stream>>>(G, counts, A);
    for (int p = 0; p < 8; ++p) {
        k_panel<<<NMAT, 512, 0, stream>>>(A, Tt, ld, p);
        int K = 7 - p;
        if (K > 0) k_syrk<<<dim3(K * (K + 1) / 2, NMAT), 256, 0, stream>>>(A, Tt, p);
    }
    k_final<<<1, 64, 0, stream>>>(ld, counts, out);
}